// Round 3
// baseline (237.154 us; speedup 1.0000x reference)
//
#include <hip/hip_runtime.h>

#define NV 128
typedef unsigned int uint32;

#define TBL_ENTRIES ((size_t)NV * NV * NV)          // 2M entries x 16 B = 32 MiB
#define TBL_OFFSET  256                              // ws[0]: absmax bits; table after
#define WS_NEED     (TBL_ENTRIES * 16 + TBL_OFFSET)

// ---------------------------------------------------------------------------
// ws[0] init (graph-safe, runs every call)
// ---------------------------------------------------------------------------
__global__ __launch_bounds__(64) void init_ws_kernel(uint32* __restrict__ m) {
    if (threadIdx.x == 0) *m = 0u;
}

// ---------------------------------------------------------------------------
// Global absmax of the grid -> ws[0] (as float bits; all values >= 0 so
// uint compare == float compare)
// ---------------------------------------------------------------------------
__global__ __launch_bounds__(256) void absmax_kernel(
        const float4* __restrict__ g4, uint32* __restrict__ m, int n4) {
    int tid = blockIdx.x * blockDim.x + threadIdx.x;
    int stride = gridDim.x * blockDim.x;
    float mm = 0.0f;
    for (int i = tid; i < n4; i += stride) {
        float4 v = g4[i];
        mm = fmaxf(mm, fmaxf(fmaxf(fabsf(v.x), fabsf(v.y)),
                             fmaxf(fabsf(v.z), fabsf(v.w))));
    }
    for (int off = 32; off > 0; off >>= 1)
        mm = fmaxf(mm, __shfl_down(mm, off));
    __shared__ float wm[4];
    int lane = threadIdx.x & 63, wv = threadIdx.x >> 6;
    if (lane == 0) wm[wv] = mm;
    __syncthreads();
    if (threadIdx.x == 0) {
        mm = fmaxf(fmaxf(wm[0], wm[1]), fmaxf(wm[2], wm[3]));
        atomicMax(m, __float_as_uint(mm));
    }
}

// ---------------------------------------------------------------------------
// Repack: entry(z,x,y) = { grid[x][y][z][0..7], grid[x][y][z+1][0..7] } int8
// scaled by 127/max. Entry = 16 B (uint4). Entry index ((z*NV+x)*NV + y):
// y innermost so a query's (y0,y0+1) pair is one 32 B contiguous read.
// Entry z=127 is never queried (z0<=126) - filled with clamped z.
// Block: x fixed, 8-row y band, all z. Grid reads are one contiguous 32 KB
// band -> LDS; writes are 128 B-contiguous chunks.
// ---------------------------------------------------------------------------
__device__ __forceinline__ uint32 pack4(float4 v, float inv) {
    uint32 a = (uint32)__float2int_rn(v.x * inv) & 255u;
    uint32 b = (uint32)__float2int_rn(v.y * inv) & 255u;
    uint32 c = (uint32)__float2int_rn(v.z * inv) & 255u;
    uint32 d = (uint32)__float2int_rn(v.w * inv) & 255u;
    return a | (b << 8) | (c << 16) | (d << 24);
}

__global__ __launch_bounds__(256) void repack_q8_kernel(
        const float* __restrict__ grid, const uint32* __restrict__ mbits,
        uint4* __restrict__ tbl) {
    __shared__ float4 lds[2048];                     // [yy][z][2] = 32 KB
    int x = blockIdx.x >> 4;
    int y0 = (blockIdx.x & 15) << 3;
    int tid = threadIdx.x;

    const float4* src = reinterpret_cast<const float4*>(grid)
                      + (size_t)(x * NV + y0) * NV * 2;
    #pragma unroll
    for (int i = tid; i < 2048; i += 256) lds[i] = src[i];
    __syncthreads();

    float inv = 127.0f / __uint_as_float(*mbits);

    #pragma unroll
    for (int L = tid; L < 1024; L += 256) {
        int z = L >> 3, yy = L & 7;
        int base = (yy * NV + z) * 2;
        int nz = (z < NV - 1) ? base + 2 : base;     // z+1 clamped
        float4 a0 = lds[base], a1 = lds[base + 1];   // z   params 0-7
        float4 b0 = lds[nz],   b1 = lds[nz + 1];     // z+1 params 0-7
        uint4 p;
        p.x = pack4(a0, inv);
        p.y = pack4(a1, inv);
        p.z = pack4(b0, inv);
        p.w = pack4(b1, inv);
        tbl[(size_t)((z * NV + x) * NV) + y0 + yy] = p;
    }
}

// ---------------------------------------------------------------------------
// Main gather: 4 x uint4 (64 B) per query in 2 contiguous 32 B pairs.
// ---------------------------------------------------------------------------
__device__ __forceinline__ float4 dec4(uint32 w) {
    return make_float4((float)((int)(w << 24) >> 24),
                       (float)((int)(w << 16) >> 24),
                       (float)((int)(w <<  8) >> 24),
                       (float)((int)  w       >> 24));
}

__device__ __forceinline__ void acc4(float4& a, float4 v, float w) {
    a.x = fmaf(v.x, w, a.x);
    a.y = fmaf(v.y, w, a.y);
    a.z = fmaf(v.z, w, a.z);
    a.w = fmaf(v.w, w, a.w);
}

__global__ __launch_bounds__(256) void trilerp_q8_kernel(
        const float* __restrict__ ipos, const uint4* __restrict__ tbl,
        const uint32* __restrict__ mbits, float* __restrict__ out, int nq) {
    __shared__ float4 pls[192];                      // 256 queries x 12 B
    int tid = threadIdx.x;
    int blk = blockIdx.x;
    const float4* ip4 = reinterpret_cast<const float4*>(ipos);
    int n4p = (int)(((long long)nq * 3) >> 2);
    int sbase = blk * 192;
    if (tid < 192 && sbase + tid < n4p) pls[tid] = ip4[sbase + tid];
    __syncthreads();

    int q = blk * 256 + tid;
    if (q >= nq) return;

    const float* pf = reinterpret_cast<const float*>(pls);
    float px = pf[tid * 3 + 0];
    float py = pf[tid * 3 + 1];
    float pz = pf[tid * 3 + 2];

    px = fminf(fmaxf(px, 0.0f), 1.0f) * (float)(NV - 1);
    py = fminf(fmaxf(py, 0.0f), 1.0f) * (float)(NV - 1);
    pz = fminf(fmaxf(pz, 0.0f), 1.0f) * (float)(NV - 1);

    int x0 = min((int)px, NV - 2);
    int y0 = min((int)py, NV - 2);
    int z0 = min((int)pz, NV - 2);

    float fx = px - (float)x0;
    float fy = py - (float)y0;
    float fz = pz - (float)z0;
    float gx = 1.0f - fx, gy = 1.0f - fy, gz = 1.0f - fz;

    int e = (z0 * NV + x0) * NV + y0;
    uint4 A0 = tbl[e];            // (x0,y0): .x=z0 p0-3 .y=z0 p4-7 .z=z1 p0-3 .w=z1 p4-7
    uint4 A1 = tbl[e + 1];        // (x0,y1)
    uint4 B0 = tbl[e + NV];       // (x1,y0)
    uint4 B1 = tbl[e + NV + 1];   // (x1,y1)

    float s = __uint_as_float(*mbits) * (1.0f / 127.0f);

    float w00 = gx * gy, w01 = gx * fy, w10 = fx * gy, w11 = fx * fy;

    float4 a03 = make_float4(0.f, 0.f, 0.f, 0.f);
    float4 a47 = make_float4(0.f, 0.f, 0.f, 0.f);

    {
        float wg = w00 * gz, wf = w00 * fz;
        acc4(a03, dec4(A0.x), wg); acc4(a03, dec4(A0.z), wf);
        acc4(a47, dec4(A0.y), wg); acc4(a47, dec4(A0.w), wf);
    }
    {
        float wg = w01 * gz, wf = w01 * fz;
        acc4(a03, dec4(A1.x), wg); acc4(a03, dec4(A1.z), wf);
        acc4(a47, dec4(A1.y), wg); acc4(a47, dec4(A1.w), wf);
    }
    {
        float wg = w10 * gz, wf = w10 * fz;
        acc4(a03, dec4(B0.x), wg); acc4(a03, dec4(B0.z), wf);
        acc4(a47, dec4(B0.y), wg); acc4(a47, dec4(B0.w), wf);
    }
    {
        float wg = w11 * gz, wf = w11 * fz;
        acc4(a03, dec4(B1.x), wg); acc4(a03, dec4(B1.z), wf);
        acc4(a47, dec4(B1.y), wg); acc4(a47, dec4(B1.w), wf);
    }

    float4* o4 = reinterpret_cast<float4*>(out);
    o4[q * 2 + 0] = make_float4(a03.x * s, a03.y * s, a03.z * s, a03.w * s);
    o4[q * 2 + 1] = make_float4(a47.x * s, a47.y * s, a47.z * s, a47.w * s);
}

// ---------------------------------------------------------------------------
// Fallback (direct fp32 gather) if workspace can't hold the table.
// ---------------------------------------------------------------------------
__device__ __forceinline__ float4 lerp4(float4 a, float4 b, float t) {
    return make_float4(fmaf(t, b.x - a.x, a.x),
                       fmaf(t, b.y - a.y, a.y),
                       fmaf(t, b.z - a.z, a.z),
                       fmaf(t, b.w - a.w, a.w));
}

__global__ __launch_bounds__(256) void voxel_trilerp_kernel(
        const float* __restrict__ ipos,
        const float* __restrict__ grid,
        float* __restrict__ out,
        int nq) {
    const int tid = blockIdx.x * blockDim.x + threadIdx.x;
    const int stride = gridDim.x * blockDim.x;
    const float4* __restrict__ g4 = reinterpret_cast<const float4*>(grid);
    float4* __restrict__ o4 = reinterpret_cast<float4*>(out);

    const int Z4 = 2;
    const int Y4 = NV * 8 / 4;
    const int X4 = NV * NV * 8 / 4;

    for (int q = tid; q < nq; q += stride) {
        float px = ipos[q * 3 + 0];
        float py = ipos[q * 3 + 1];
        float pz = ipos[q * 3 + 2];

        px = fminf(fmaxf(px, 0.0f), 1.0f) * (float)(NV - 1);
        py = fminf(fmaxf(py, 0.0f), 1.0f) * (float)(NV - 1);
        pz = fminf(fmaxf(pz, 0.0f), 1.0f) * (float)(NV - 1);

        int x0 = min((int)px, NV - 2);
        int y0 = min((int)py, NV - 2);
        int z0 = min((int)pz, NV - 2);

        float fx = px - (float)x0;
        float fy = py - (float)y0;
        float fz = pz - (float)z0;

        int b = x0 * X4 + y0 * Y4 + z0 * Z4;

        float4 c00a0 = g4[b],                c00a1 = g4[b + 1];
        float4 c00b0 = g4[b + Z4],           c00b1 = g4[b + Z4 + 1];
        float4 c01a0 = g4[b + Y4],           c01a1 = g4[b + Y4 + 1];
        float4 c01b0 = g4[b + Y4 + Z4],      c01b1 = g4[b + Y4 + Z4 + 1];
        float4 c10a0 = g4[b + X4],           c10a1 = g4[b + X4 + 1];
        float4 c10b0 = g4[b + X4 + Z4],      c10b1 = g4[b + X4 + Z4 + 1];
        float4 c11a0 = g4[b + X4 + Y4],      c11a1 = g4[b + X4 + Y4 + 1];
        float4 c11b0 = g4[b + X4 + Y4 + Z4], c11b1 = g4[b + X4 + Y4 + Z4 + 1];

        float4 z00_0 = lerp4(c00a0, c00b0, fz), z00_1 = lerp4(c00a1, c00b1, fz);
        float4 z01_0 = lerp4(c01a0, c01b0, fz), z01_1 = lerp4(c01a1, c01b1, fz);
        float4 z10_0 = lerp4(c10a0, c10b0, fz), z10_1 = lerp4(c10a1, c10b1, fz);
        float4 z11_0 = lerp4(c11a0, c11b0, fz), z11_1 = lerp4(c11a1, c11b1, fz);

        float4 y0_0 = lerp4(z00_0, z01_0, fy), y0_1 = lerp4(z00_1, z01_1, fy);
        float4 y1_0 = lerp4(z10_0, z11_0, fy), y1_1 = lerp4(z10_1, z11_1, fy);

        float4 r0 = lerp4(y0_0, y1_0, fx);
        float4 r1 = lerp4(y0_1, y1_1, fx);

        o4[q * 2 + 0] = r0;
        o4[q * 2 + 1] = r1;
    }
}

extern "C" void kernel_launch(void* const* d_in, const int* in_sizes, int n_in,
                              void* d_out, int out_size, void* d_ws, size_t ws_size,
                              hipStream_t stream) {
    const float* ipos = (const float*)d_in[0];
    const float* grid = (const float*)d_in[1];
    float* out = (float*)d_out;

    const int nq = in_sizes[0] / 3;           // 4194304
    const int ng4 = in_sizes[1] / 4;          // 4194304 float4s

    if (ws_size >= WS_NEED) {
        uint32* mbits = (uint32*)d_ws;
        uint4* tbl = (uint4*)((char*)d_ws + TBL_OFFSET);

        init_ws_kernel<<<1, 64, 0, stream>>>(mbits);
        absmax_kernel<<<2048, 256, 0, stream>>>(
            reinterpret_cast<const float4*>(grid), mbits, ng4);
        repack_q8_kernel<<<NV * 16, 256, 0, stream>>>(grid, mbits, tbl);
        trilerp_q8_kernel<<<(nq + 255) / 256, 256, 0, stream>>>(
            ipos, tbl, mbits, out, nq);
    } else {
        voxel_trilerp_kernel<<<2048, 256, 0, stream>>>(ipos, grid, out, nq);
    }
}

// Round 4
// 192.870 us; speedup vs baseline: 1.2296x; 1.2296x over previous
//
#include <hip/hip_runtime.h>

#define NV 128
typedef unsigned int uint32;

#define TBL_ENTRIES ((size_t)NV * NV * NV)           // 2M entries x 64 B = 128 MiB
#define TBL_BYTES   (TBL_ENTRIES * 64)
// absmax bits live inside the LAST entry (x=y=z=127), which the main kernel
// can never read (x0,y0,z0 <= NV-2). Repack skips that entry.

// ---------------------------------------------------------------------------
__global__ __launch_bounds__(64) void init_ws_kernel(uint32* __restrict__ m) {
    if (threadIdx.x == 0) *m = 0u;
}

// Global absmax of grid -> *m as float bits (values >= 0: uint cmp == float cmp)
__global__ __launch_bounds__(256) void absmax_kernel(
        const float4* __restrict__ g4, uint32* __restrict__ m, int n4) {
    int tid = blockIdx.x * blockDim.x + threadIdx.x;
    int stride = gridDim.x * blockDim.x;
    float mm = 0.0f;
    for (int i = tid; i < n4; i += stride) {
        float4 v = g4[i];
        mm = fmaxf(mm, fmaxf(fmaxf(fabsf(v.x), fabsf(v.y)),
                             fmaxf(fabsf(v.z), fabsf(v.w))));
    }
    for (int off = 32; off > 0; off >>= 1)
        mm = fmaxf(mm, __shfl_down(mm, off));
    __shared__ float wm[4];
    int lane = threadIdx.x & 63, wv = threadIdx.x >> 6;
    if (lane == 0) wm[wv] = mm;
    __syncthreads();
    if (threadIdx.x == 0) {
        mm = fmaxf(fmaxf(wm[0], wm[1]), fmaxf(wm[2], wm[3]));
        atomicMax(m, __float_as_uint(mm));
    }
}

// ---------------------------------------------------------------------------
// Full-replication repack: entry(x,y,z) = all 8 corners (x+xr,y+yr,z+zr),
// 8 params each, int8 * (127/absmax). Entry = 64 B (4 x uint4), 64-aligned.
// uint4 r: r0=(y,  z|z1) pair? No -- layout per (X,Y) row:
//   E[r] for r in {(x,y),(x,y1),(x1,y),(x1,y1)}:
//     E.x = z  params0-3, E.y = z  params4-7, E.z = z1 params0-3, E.w = z1 p4-7
// Entry index e = (x*NV + y)*NV + z  (z innermost -> consecutive threads
// write consecutive 64-B entries; reads stream 4 rows with L1/L2 reuse).
// ---------------------------------------------------------------------------
__device__ __forceinline__ uint32 pack4(float4 v, float inv) {
    uint32 a = (uint32)__float2int_rn(v.x * inv) & 255u;
    uint32 b = (uint32)__float2int_rn(v.y * inv) & 255u;
    uint32 c = (uint32)__float2int_rn(v.z * inv) & 255u;
    uint32 d = (uint32)__float2int_rn(v.w * inv) & 255u;
    return a | (b << 8) | (c << 16) | (d << 24);
}

__device__ __forceinline__ uint4 pack_row(const float4* __restrict__ g4,
                                          int X, int Y, int z, int z1, float inv) {
    int b  = ((X * NV + Y) * NV + z ) * 2;
    int bz = ((X * NV + Y) * NV + z1) * 2;
    float4 a0 = g4[b],  a1 = g4[b + 1];
    float4 c0 = g4[bz], c1 = g4[bz + 1];
    uint4 E;
    E.x = pack4(a0, inv); E.y = pack4(a1, inv);
    E.z = pack4(c0, inv); E.w = pack4(c1, inv);
    return E;
}

__global__ __launch_bounds__(256) void repack_full_kernel(
        const float* __restrict__ grid, const uint32* __restrict__ mbits,
        uint4* __restrict__ tbl) {
    int t = blockIdx.x * blockDim.x + threadIdx.x;
    if (t >= (int)TBL_ENTRIES - 1) return;   // last entry holds absmax bits
    int z = t & (NV - 1);
    int y = (t >> 7) & (NV - 1);
    int x = t >> 14;
    int x1 = min(x + 1, NV - 1);
    int y1 = min(y + 1, NV - 1);
    int z1 = min(z + 1, NV - 1);

    float inv = 127.0f / __uint_as_float(*mbits);
    const float4* g4 = reinterpret_cast<const float4*>(grid);

    uint4* dst = tbl + (size_t)t * 4;
    dst[0] = pack_row(g4, x,  y,  z, z1, inv);
    dst[1] = pack_row(g4, x,  y1, z, z1, inv);
    dst[2] = pack_row(g4, x1, y,  z, z1, inv);
    dst[3] = pack_row(g4, x1, y1, z, z1, inv);
}

// ---------------------------------------------------------------------------
// Main gather: exactly one 64-B aligned entry (4 x uint4) per query.
// ---------------------------------------------------------------------------
__device__ __forceinline__ float4 dec4(uint32 w) {
    return make_float4((float)((int)(w << 24) >> 24),
                       (float)((int)(w << 16) >> 24),
                       (float)((int)(w <<  8) >> 24),
                       (float)((int)  w       >> 24));
}

__device__ __forceinline__ void acc4(float4& a, float4 v, float w) {
    a.x = fmaf(v.x, w, a.x);
    a.y = fmaf(v.y, w, a.y);
    a.z = fmaf(v.z, w, a.z);
    a.w = fmaf(v.w, w, a.w);
}

__global__ __launch_bounds__(256) void trilerp_full_kernel(
        const float* __restrict__ ipos, const uint4* __restrict__ tbl,
        const uint32* __restrict__ mbits, float* __restrict__ out, int nq) {
    __shared__ float4 pls[192];                      // 256 queries x 12 B
    int tid = threadIdx.x;
    int blk = blockIdx.x;
    const float4* ip4 = reinterpret_cast<const float4*>(ipos);
    int n4p = (int)(((long long)nq * 3) >> 2);
    int sbase = blk * 192;
    if (tid < 192 && sbase + tid < n4p) pls[tid] = ip4[sbase + tid];
    __syncthreads();

    int q = blk * 256 + tid;
    if (q >= nq) return;

    const float* pf = reinterpret_cast<const float*>(pls);
    float px = pf[tid * 3 + 0];
    float py = pf[tid * 3 + 1];
    float pz = pf[tid * 3 + 2];

    px = fminf(fmaxf(px, 0.0f), 1.0f) * (float)(NV - 1);
    py = fminf(fmaxf(py, 0.0f), 1.0f) * (float)(NV - 1);
    pz = fminf(fmaxf(pz, 0.0f), 1.0f) * (float)(NV - 1);

    int x0 = min((int)px, NV - 2);
    int y0 = min((int)py, NV - 2);
    int z0 = min((int)pz, NV - 2);

    float fx = px - (float)x0;
    float fy = py - (float)y0;
    float fz = pz - (float)z0;
    float gx = 1.0f - fx, gy = 1.0f - fy, gz = 1.0f - fz;

    size_t e = (size_t)((x0 * NV + y0) * NV + z0) * 4;
    uint4 E0 = tbl[e + 0];        // row (x0,y0): z|z1 pair
    uint4 E1 = tbl[e + 1];        // row (x0,y1)
    uint4 E2 = tbl[e + 2];        // row (x1,y0)
    uint4 E3 = tbl[e + 3];        // row (x1,y1)

    float s = __uint_as_float(*mbits) * (1.0f / 127.0f);

    float w0 = gx * gy, w1 = gx * fy, w2 = fx * gy, w3 = fx * fy;

    float4 a03 = make_float4(0.f, 0.f, 0.f, 0.f);
    float4 a47 = make_float4(0.f, 0.f, 0.f, 0.f);

    {
        float wg = w0 * gz, wf = w0 * fz;
        acc4(a03, dec4(E0.x), wg); acc4(a47, dec4(E0.y), wg);
        acc4(a03, dec4(E0.z), wf); acc4(a47, dec4(E0.w), wf);
    }
    {
        float wg = w1 * gz, wf = w1 * fz;
        acc4(a03, dec4(E1.x), wg); acc4(a47, dec4(E1.y), wg);
        acc4(a03, dec4(E1.z), wf); acc4(a47, dec4(E1.w), wf);
    }
    {
        float wg = w2 * gz, wf = w2 * fz;
        acc4(a03, dec4(E2.x), wg); acc4(a47, dec4(E2.y), wg);
        acc4(a03, dec4(E2.z), wf); acc4(a47, dec4(E2.w), wf);
    }
    {
        float wg = w3 * gz, wf = w3 * fz;
        acc4(a03, dec4(E3.x), wg); acc4(a47, dec4(E3.y), wg);
        acc4(a03, dec4(E3.z), wf); acc4(a47, dec4(E3.w), wf);
    }

    float4* o4 = reinterpret_cast<float4*>(out);
    o4[q * 2 + 0] = make_float4(a03.x * s, a03.y * s, a03.z * s, a03.w * s);
    o4[q * 2 + 1] = make_float4(a47.x * s, a47.y * s, a47.z * s, a47.w * s);
}

// ---------------------------------------------------------------------------
// Fallback (direct fp32 gather) if workspace can't hold the table.
// ---------------------------------------------------------------------------
__device__ __forceinline__ float4 lerp4(float4 a, float4 b, float t) {
    return make_float4(fmaf(t, b.x - a.x, a.x),
                       fmaf(t, b.y - a.y, a.y),
                       fmaf(t, b.z - a.z, a.z),
                       fmaf(t, b.w - a.w, a.w));
}

__global__ __launch_bounds__(256) void voxel_trilerp_kernel(
        const float* __restrict__ ipos,
        const float* __restrict__ grid,
        float* __restrict__ out,
        int nq) {
    const int tid = blockIdx.x * blockDim.x + threadIdx.x;
    const int stride = gridDim.x * blockDim.x;
    const float4* __restrict__ g4 = reinterpret_cast<const float4*>(grid);
    float4* __restrict__ o4 = reinterpret_cast<float4*>(out);

    const int Z4 = 2;
    const int Y4 = NV * 8 / 4;
    const int X4 = NV * NV * 8 / 4;

    for (int q = tid; q < nq; q += stride) {
        float px = ipos[q * 3 + 0];
        float py = ipos[q * 3 + 1];
        float pz = ipos[q * 3 + 2];

        px = fminf(fmaxf(px, 0.0f), 1.0f) * (float)(NV - 1);
        py = fminf(fmaxf(py, 0.0f), 1.0f) * (float)(NV - 1);
        pz = fminf(fmaxf(pz, 0.0f), 1.0f) * (float)(NV - 1);

        int x0 = min((int)px, NV - 2);
        int y0 = min((int)py, NV - 2);
        int z0 = min((int)pz, NV - 2);

        float fx = px - (float)x0;
        float fy = py - (float)y0;
        float fz = pz - (float)z0;

        int b = x0 * X4 + y0 * Y4 + z0 * Z4;

        float4 c00a0 = g4[b],                c00a1 = g4[b + 1];
        float4 c00b0 = g4[b + Z4],           c00b1 = g4[b + Z4 + 1];
        float4 c01a0 = g4[b + Y4],           c01a1 = g4[b + Y4 + 1];
        float4 c01b0 = g4[b + Y4 + Z4],      c01b1 = g4[b + Y4 + Z4 + 1];
        float4 c10a0 = g4[b + X4],           c10a1 = g4[b + X4 + 1];
        float4 c10b0 = g4[b + X4 + Z4],      c10b1 = g4[b + X4 + Z4 + 1];
        float4 c11a0 = g4[b + X4 + Y4],      c11a1 = g4[b + X4 + Y4 + 1];
        float4 c11b0 = g4[b + X4 + Y4 + Z4], c11b1 = g4[b + X4 + Y4 + Z4 + 1];

        float4 z00_0 = lerp4(c00a0, c00b0, fz), z00_1 = lerp4(c00a1, c00b1, fz);
        float4 z01_0 = lerp4(c01a0, c01b0, fz), z01_1 = lerp4(c01a1, c01b1, fz);
        float4 z10_0 = lerp4(c10a0, c10b0, fz), z10_1 = lerp4(c10a1, c10b1, fz);
        float4 z11_0 = lerp4(c11a0, c11b0, fz), z11_1 = lerp4(c11a1, c11b1, fz);

        float4 y0_0 = lerp4(z00_0, z01_0, fy), y0_1 = lerp4(z00_1, z01_1, fy);
        float4 y1_0 = lerp4(z10_0, z11_0, fy), y1_1 = lerp4(z10_1, z11_1, fy);

        float4 r0 = lerp4(y0_0, y1_0, fx);
        float4 r1 = lerp4(y0_1, y1_1, fx);

        o4[q * 2 + 0] = r0;
        o4[q * 2 + 1] = r1;
    }
}

extern "C" void kernel_launch(void* const* d_in, const int* in_sizes, int n_in,
                              void* d_out, int out_size, void* d_ws, size_t ws_size,
                              hipStream_t stream) {
    const float* ipos = (const float*)d_in[0];
    const float* grid = (const float*)d_in[1];
    float* out = (float*)d_out;

    const int nq = in_sizes[0] / 3;           // 4194304
    const int ng4 = in_sizes[1] / 4;          // 4194304 float4s

    if (ws_size >= TBL_BYTES) {
        uint4* tbl = (uint4*)d_ws;
        // absmax bits inside the never-read last entry (x=y=z=127)
        uint32* mbits = (uint32*)((char*)d_ws + TBL_BYTES - 64);

        init_ws_kernel<<<1, 64, 0, stream>>>(mbits);
        absmax_kernel<<<2048, 256, 0, stream>>>(
            reinterpret_cast<const float4*>(grid), mbits, ng4);
        repack_full_kernel<<<(int)(TBL_ENTRIES / 256), 256, 0, stream>>>(
            grid, mbits, tbl);
        trilerp_full_kernel<<<(nq + 255) / 256, 256, 0, stream>>>(
            ipos, tbl, mbits, out, nq);
    } else {
        voxel_trilerp_kernel<<<2048, 256, 0, stream>>>(ipos, grid, out, nq);
    }
}

// Round 5
// 168.730 us; speedup vs baseline: 1.4055x; 1.1431x over previous
//
#include <hip/hip_runtime.h>

#define NV 128
typedef unsigned int uint32;

#define TBL_ENTRIES ((size_t)NV * NV * NV)           // 2M entries x 64 B = 128 MiB
#define TBL_BYTES   (TBL_ENTRIES * 64)
// The x=127 plane of the table (last 128*128 entries = 1 MiB) is NEVER read
// by the main kernel (x0,y0,z0 <= 126) and never written by repack.
// We place scratch there:
//   M  = ws + TBL_BYTES - 4096        : 1024 per-block absmax partials
//   S  = ws + TBL_BYTES - 4096 - 64   : final absmax (float)

// ---------------------------------------------------------------------------
// Per-block absmax partials (no init, no atomics: plain overwrite).
// ---------------------------------------------------------------------------
__global__ __launch_bounds__(256) void absmax_kernel(
        const float4* __restrict__ g4, float* __restrict__ M, int n4) {
    int tid = blockIdx.x * blockDim.x + threadIdx.x;
    int stride = gridDim.x * blockDim.x;
    float mm = 0.0f;
    for (int i = tid; i < n4; i += stride) {
        float4 v = g4[i];
        mm = fmaxf(mm, fmaxf(fmaxf(fabsf(v.x), fabsf(v.y)),
                             fmaxf(fabsf(v.z), fabsf(v.w))));
    }
    for (int off = 32; off > 0; off >>= 1)
        mm = fmaxf(mm, __shfl_down(mm, off));
    __shared__ float wm[4];
    int lane = threadIdx.x & 63, wv = threadIdx.x >> 6;
    if (lane == 0) wm[wv] = mm;
    __syncthreads();
    if (threadIdx.x == 0)
        M[blockIdx.x] = fmaxf(fmaxf(wm[0], wm[1]), fmaxf(wm[2], wm[3]));
}

// ---------------------------------------------------------------------------
// LDS-tiled full-replication repack.
// Block = (x, y-band of 4), x in [0,126]. Stages rows (x..x+1, y0..y0+4)
// = 10 rows x 4 KB into LDS (coalesced), reduces the absmax partials, then
// each thread emits one 16-B table word per iteration (coalesced writes).
// Entry(x,y,z) = 4 uint4 words w=(xr*2+yr):
//   word = { pack(z p0-3), pack(z p4-7), pack(z1 p0-3), pack(z1 p4-7) }
//   for corner row (x+xr, y+yr).
// ---------------------------------------------------------------------------
__device__ __forceinline__ uint32 pack4(float4 v, float inv) {
    uint32 a = (uint32)__float2int_rn(v.x * inv) & 255u;
    uint32 b = (uint32)__float2int_rn(v.y * inv) & 255u;
    uint32 c = (uint32)__float2int_rn(v.z * inv) & 255u;
    uint32 d = (uint32)__float2int_rn(v.w * inv) & 255u;
    return a | (b << 8) | (c << 16) | (d << 24);
}

#define ROWSTRIDE 257   // float4 units per staged row (+1 pad vs 256)

__global__ __launch_bounds__(256) void repack_full_kernel(
        const float* __restrict__ grid, const float* __restrict__ M,
        float* __restrict__ S, uint4* __restrict__ tbl) {
    __shared__ float4 lds4[10 * ROWSTRIDE];          // 10 rows -> ~41 KB
    __shared__ float wm[4];
    int tid = threadIdx.x;
    int x  = blockIdx.x >> 5;                        // 0..126
    int y0 = (blockIdx.x & 31) << 2;                 // 0,4,...,124

    // Stage 10 grid rows: r = xi*5 + yj, xi in {0,1}, yj in {0..4}
    const float4* g4 = reinterpret_cast<const float4*>(grid);
    for (int i = tid; i < 10 * 256; i += 256) {
        int r = i >> 8, c = i & 255;
        int xi = r / 5, yj = r - xi * 5;
        int gx_ = min(x + xi, NV - 1);
        int gy_ = min(y0 + yj, NV - 1);
        lds4[r * ROWSTRIDE + c] = g4[(size_t)(gx_ * NV + gy_) * 256 + c];
    }

    // Reduce the 1024 absmax partials (4 KB, L2-hot)
    const float4* M4 = reinterpret_cast<const float4*>(M);
    float4 mv = M4[tid];
    float mm = fmaxf(fmaxf(mv.x, mv.y), fmaxf(mv.z, mv.w));
    for (int off = 32; off > 0; off >>= 1)
        mm = fmaxf(mm, __shfl_down(mm, off));
    int lane = tid & 63, wv = tid >> 6;
    if (lane == 0) wm[wv] = mm;
    __syncthreads();
    float amax = fmaxf(fmaxf(wm[0], wm[1]), fmaxf(wm[2], wm[3]));
    if (blockIdx.x == 0 && tid == 0) *S = amax;
    float inv = 127.0f / amax;

    // Emit 4 entries/thread-row band: 4 y * 128 z * 4 words = 2048 words
    for (int i = tid; i < 2048; i += 256) {
        int L = i >> 2, w = i & 3;                   // entry-in-band, word
        int z = L & 127, yy = L >> 7;                // yy in 0..3
        int xr = w >> 1, yr = w & 1;
        int row = xr * 5 + yy + yr;
        int z1 = min(z + 1, NV - 1);
        float4 a0 = lds4[row * ROWSTRIDE + z * 2];
        float4 a1 = lds4[row * ROWSTRIDE + z * 2 + 1];
        float4 b0 = lds4[row * ROWSTRIDE + z1 * 2];
        float4 b1 = lds4[row * ROWSTRIDE + z1 * 2 + 1];
        uint4 word;
        word.x = pack4(a0, inv);
        word.y = pack4(a1, inv);
        word.z = pack4(b0, inv);
        word.w = pack4(b1, inv);
        size_t e = (size_t)((x * NV) + y0 + yy) * NV + z;
        tbl[e * 4 + w] = word;
    }
}

// ---------------------------------------------------------------------------
// Main gather: 2 queries/thread, one 64-B aligned entry per query.
// ---------------------------------------------------------------------------
__device__ __forceinline__ float4 dec4(uint32 w) {
    return make_float4((float)((int)(w << 24) >> 24),
                       (float)((int)(w << 16) >> 24),
                       (float)((int)(w <<  8) >> 24),
                       (float)((int)  w       >> 24));
}

__device__ __forceinline__ void acc4(float4& a, float4 v, float w) {
    a.x = fmaf(v.x, w, a.x);
    a.y = fmaf(v.y, w, a.y);
    a.z = fmaf(v.z, w, a.z);
    a.w = fmaf(v.w, w, a.w);
}

__device__ __forceinline__ void cell_of(const float* pf, int slot,
                                        size_t& e, float& fx, float& fy, float& fz) {
    float px = pf[slot * 3 + 0];
    float py = pf[slot * 3 + 1];
    float pz = pf[slot * 3 + 2];
    px = fminf(fmaxf(px, 0.0f), 1.0f) * (float)(NV - 1);
    py = fminf(fmaxf(py, 0.0f), 1.0f) * (float)(NV - 1);
    pz = fminf(fmaxf(pz, 0.0f), 1.0f) * (float)(NV - 1);
    int x0 = min((int)px, NV - 2);
    int y0 = min((int)py, NV - 2);
    int z0 = min((int)pz, NV - 2);
    fx = px - (float)x0;
    fy = py - (float)y0;
    fz = pz - (float)z0;
    e = (size_t)((x0 * NV + y0) * NV + z0) * 4;
}

__device__ __forceinline__ void lerp_store(const uint4* E, float fx, float fy,
                                           float fz, float s, float4* o4, int q) {
    float gx = 1.0f - fx, gy = 1.0f - fy, gz = 1.0f - fz;
    float w0 = gx * gy, w1 = gx * fy, w2 = fx * gy, w3 = fx * fy;
    float4 a03 = make_float4(0.f, 0.f, 0.f, 0.f);
    float4 a47 = make_float4(0.f, 0.f, 0.f, 0.f);
    {
        float wg = w0 * gz, wf = w0 * fz;
        acc4(a03, dec4(E[0].x), wg); acc4(a47, dec4(E[0].y), wg);
        acc4(a03, dec4(E[0].z), wf); acc4(a47, dec4(E[0].w), wf);
    }
    {
        float wg = w1 * gz, wf = w1 * fz;
        acc4(a03, dec4(E[1].x), wg); acc4(a47, dec4(E[1].y), wg);
        acc4(a03, dec4(E[1].z), wf); acc4(a47, dec4(E[1].w), wf);
    }
    {
        float wg = w2 * gz, wf = w2 * fz;
        acc4(a03, dec4(E[2].x), wg); acc4(a47, dec4(E[2].y), wg);
        acc4(a03, dec4(E[2].z), wf); acc4(a47, dec4(E[2].w), wf);
    }
    {
        float wg = w3 * gz, wf = w3 * fz;
        acc4(a03, dec4(E[3].x), wg); acc4(a47, dec4(E[3].y), wg);
        acc4(a03, dec4(E[3].z), wf); acc4(a47, dec4(E[3].w), wf);
    }
    o4[q * 2 + 0] = make_float4(a03.x * s, a03.y * s, a03.z * s, a03.w * s);
    o4[q * 2 + 1] = make_float4(a47.x * s, a47.y * s, a47.z * s, a47.w * s);
}

__global__ __launch_bounds__(256) void trilerp_full_kernel(
        const float* __restrict__ ipos, const uint4* __restrict__ tbl,
        const float* __restrict__ S, float* __restrict__ out, int nq) {
    __shared__ float4 pls[384];                      // 512 queries x 12 B
    int tid = threadIdx.x;
    int blk = blockIdx.x;
    const float4* ip4 = reinterpret_cast<const float4*>(ipos);
    int n4p = (int)(((long long)nq * 3) >> 2);
    int sbase = blk * 384;
    #pragma unroll
    for (int k = 0; k < 2; ++k) {
        int i = tid + k * 256;
        if (i < 384 && sbase + i < n4p) pls[i] = ip4[sbase + i];
    }
    __syncthreads();

    int q0 = blk * 512 + tid;
    int q1 = q0 + 256;
    const float* pf = reinterpret_cast<const float*>(pls);
    float s = (*S) * (1.0f / 127.0f);
    float4* o4 = reinterpret_cast<float4*>(out);

    size_t e0 = 0, e1 = 0;
    float fx0, fy0, fz0, fx1, fy1, fz1;
    bool v0 = q0 < nq, v1 = q1 < nq;
    if (v0) cell_of(pf, tid,       e0, fx0, fy0, fz0);
    if (v1) cell_of(pf, tid + 256, e1, fx1, fy1, fz1);

    uint4 E0[4], E1[4];
    if (v0) { E0[0] = tbl[e0]; E0[1] = tbl[e0+1]; E0[2] = tbl[e0+2]; E0[3] = tbl[e0+3]; }
    if (v1) { E1[0] = tbl[e1]; E1[1] = tbl[e1+1]; E1[2] = tbl[e1+2]; E1[3] = tbl[e1+3]; }

    if (v0) lerp_store(E0, fx0, fy0, fz0, s, o4, q0);
    if (v1) lerp_store(E1, fx1, fy1, fz1, s, o4, q1);
}

// ---------------------------------------------------------------------------
// Fallback (direct fp32 gather) if workspace can't hold the table.
// ---------------------------------------------------------------------------
__device__ __forceinline__ float4 lerp4(float4 a, float4 b, float t) {
    return make_float4(fmaf(t, b.x - a.x, a.x),
                       fmaf(t, b.y - a.y, a.y),
                       fmaf(t, b.z - a.z, a.z),
                       fmaf(t, b.w - a.w, a.w));
}

__global__ __launch_bounds__(256) void voxel_trilerp_kernel(
        const float* __restrict__ ipos,
        const float* __restrict__ grid,
        float* __restrict__ out,
        int nq) {
    const int tid = blockIdx.x * blockDim.x + threadIdx.x;
    const int stride = gridDim.x * blockDim.x;
    const float4* __restrict__ g4 = reinterpret_cast<const float4*>(grid);
    float4* __restrict__ o4 = reinterpret_cast<float4*>(out);

    const int Z4 = 2;
    const int Y4 = NV * 8 / 4;
    const int X4 = NV * NV * 8 / 4;

    for (int q = tid; q < nq; q += stride) {
        float px = ipos[q * 3 + 0];
        float py = ipos[q * 3 + 1];
        float pz = ipos[q * 3 + 2];

        px = fminf(fmaxf(px, 0.0f), 1.0f) * (float)(NV - 1);
        py = fminf(fmaxf(py, 0.0f), 1.0f) * (float)(NV - 1);
        pz = fminf(fmaxf(pz, 0.0f), 1.0f) * (float)(NV - 1);

        int x0 = min((int)px, NV - 2);
        int y0 = min((int)py, NV - 2);
        int z0 = min((int)pz, NV - 2);

        float fx = px - (float)x0;
        float fy = py - (float)y0;
        float fz = pz - (float)z0;

        int b = x0 * X4 + y0 * Y4 + z0 * Z4;

        float4 c00a0 = g4[b],                c00a1 = g4[b + 1];
        float4 c00b0 = g4[b + Z4],           c00b1 = g4[b + Z4 + 1];
        float4 c01a0 = g4[b + Y4],           c01a1 = g4[b + Y4 + 1];
        float4 c01b0 = g4[b + Y4 + Z4],      c01b1 = g4[b + Y4 + Z4 + 1];
        float4 c10a0 = g4[b + X4],           c10a1 = g4[b + X4 + 1];
        float4 c10b0 = g4[b + X4 + Z4],      c10b1 = g4[b + X4 + Z4 + 1];
        float4 c11a0 = g4[b + X4 + Y4],      c11a1 = g4[b + X4 + Y4 + 1];
        float4 c11b0 = g4[b + X4 + Y4 + Z4], c11b1 = g4[b + X4 + Y4 + Z4 + 1];

        float4 z00_0 = lerp4(c00a0, c00b0, fz), z00_1 = lerp4(c00a1, c00b1, fz);
        float4 z01_0 = lerp4(c01a0, c01b0, fz), z01_1 = lerp4(c01a1, c01b1, fz);
        float4 z10_0 = lerp4(c10a0, c10b0, fz), z10_1 = lerp4(c10a1, c10b1, fz);
        float4 z11_0 = lerp4(c11a0, c11b0, fz), z11_1 = lerp4(c11a1, c11b1, fz);

        float4 y0_0 = lerp4(z00_0, z01_0, fy), y0_1 = lerp4(z00_1, z01_1, fy);
        float4 y1_0 = lerp4(z10_0, z11_0, fy), y1_1 = lerp4(z10_1, z11_1, fy);

        float4 r0 = lerp4(y0_0, y1_0, fx);
        float4 r1 = lerp4(y0_1, y1_1, fx);

        o4[q * 2 + 0] = r0;
        o4[q * 2 + 1] = r1;
    }
}

extern "C" void kernel_launch(void* const* d_in, const int* in_sizes, int n_in,
                              void* d_out, int out_size, void* d_ws, size_t ws_size,
                              hipStream_t stream) {
    const float* ipos = (const float*)d_in[0];
    const float* grid = (const float*)d_in[1];
    float* out = (float*)d_out;

    const int nq = in_sizes[0] / 3;           // 4194304
    const int ng4 = in_sizes[1] / 4;          // 4194304 float4s

    if (ws_size >= TBL_BYTES) {
        uint4* tbl = (uint4*)d_ws;
        float* M = (float*)((char*)d_ws + TBL_BYTES - 4096);        // 1024 partials
        float* S = (float*)((char*)d_ws + TBL_BYTES - 4096 - 64);   // final absmax

        absmax_kernel<<<1024, 256, 0, stream>>>(
            reinterpret_cast<const float4*>(grid), M, ng4);
        repack_full_kernel<<<127 * 32, 256, 0, stream>>>(grid, M, S, tbl);
        trilerp_full_kernel<<<(nq + 511) / 512, 256, 0, stream>>>(
            ipos, tbl, S, out, nq);
    } else {
        voxel_trilerp_kernel<<<2048, 256, 0, stream>>>(ipos, grid, out, nq);
    }
}